// Round 15
// baseline (765.633 us; speedup 1.0000x reference)
//
#include <hip/hip_runtime.h>
#include <hip/hip_bf16.h>

#define D_MODEL 4096
#define NEXP    16
#define HID     688
#define HIDP    704
#define NSEL    4
#define NTOK    4096

typedef __attribute__((ext_vector_type(4))) float  f32x4;
typedef __attribute__((ext_vector_type(8))) short  bf16x8;

#define VMCNT(n) asm volatile("s_waitcnt vmcnt(" #n ")" ::: "memory")

__device__ __forceinline__ short f2bf(float f) {
  __hip_bfloat16 h = __float2bfloat16(f);
  return __builtin_bit_cast(short, h);
}

__device__ __forceinline__ float bf2f(short s) {
  const unsigned u = ((unsigned)(unsigned short)s) << 16;
  return __builtin_bit_cast(float, u);
}

__device__ __forceinline__ void gload16(const void* g, void* l) {
  __builtin_amdgcn_global_load_lds(
      (const __attribute__((address_space(1))) unsigned int*)g,
      (__attribute__((address_space(3))) unsigned int*)l, 16, 0, 0);
}

// ---------------------------------------------------------------- zero init
__global__ void zero_meta_kernel(int* counts, float* importance) {
  const int tid = threadIdx.x;
  if (tid < NEXP) counts[tid] = 0;
  else if (tid < 2 * NEXP) importance[tid - NEXP] = 0.f;
}

__global__ void zero_y_kernel(float* __restrict__ y) {
  const size_t i = (size_t)blockIdx.x * 256 + threadIdx.x;
  *(f32x4*)(y + i * 4) = f32x4{0.f, 0.f, 0.f, 0.f};
}

// ---------------------------------------------------------------- fused gate + conv_wgu + conv_wd (all BW-bound; interleaved)
// bid&3: 0 -> conv_wgu (2048 blocks), 1 -> conv_wd (2048), 2|3 -> gate (4096)
__global__ __launch_bounds__(256) void gate_conv_kernel(
    const float* __restrict__ x, const float* __restrict__ wg,
    int* __restrict__ counts, float* __restrict__ importance,
    int* __restrict__ pair_tok, float* __restrict__ pair_scr,
    int* __restrict__ pair_rank, short* __restrict__ xb,
    const float* __restrict__ w_g, const float* __restrict__ w_u,
    short* __restrict__ gb, short* __restrict__ ub,
    const float* __restrict__ w_d, short* __restrict__ wdb)
{
  __shared__ double red[4][NEXP];
  const int tid = threadIdx.x;
  const int r4  = blockIdx.x & 3;
  const int b4  = blockIdx.x >> 2;

  if (r4 == 0) {
    const size_t stride = (size_t)2048 * 256;
    const size_t n8 = (size_t)NEXP * HIDP * (D_MODEL / 8);
    for (size_t i = (size_t)b4 * 256 + tid; i < n8; i += stride) {
      const int c8  = (int)(i & 511);
      const int row = (int)((i >> 9) % HIDP);
      const int e   = (int)(i / (512 * HIDP));
      bf16x8 og, ou;
      if (row < HID) {
        const size_t so = ((size_t)e * HID + row) * D_MODEL + (size_t)c8 * 8;
        const f32x4 ga  = *(const f32x4*)(w_g + so);
        const f32x4 gbv = *(const f32x4*)(w_g + so + 4);
        const f32x4 ua  = *(const f32x4*)(w_u + so);
        const f32x4 ubv = *(const f32x4*)(w_u + so + 4);
        #pragma unroll
        for (int j = 0; j < 4; ++j) {
          og[j] = f2bf(ga[j]); og[4 + j] = f2bf(gbv[j]);
          ou[j] = f2bf(ua[j]); ou[4 + j] = f2bf(ubv[j]);
        }
      } else {
        #pragma unroll
        for (int j = 0; j < 8; ++j) { og[j] = 0; ou[j] = 0; }
      }
      *(bf16x8*)(gb + i * 8) = og;
      *(bf16x8*)(ub + i * 8) = ou;
    }
    return;
  }

  if (r4 == 1) {
    const size_t stride = (size_t)2048 * 256;
    const size_t n8 = (size_t)NEXP * D_MODEL * (HIDP / 8);
    for (size_t i = (size_t)b4 * 256 + tid; i < n8; i += stride) {
      const int c8  = (int)(i % 88);
      const int row = (int)((i / 88) & (D_MODEL - 1));
      const int e   = (int)(i / (88 * D_MODEL));
      bf16x8 o;
      if (c8 < 86) {
        const size_t so = ((size_t)e * D_MODEL + row) * HID + (size_t)c8 * 8;
        const f32x4 a = *(const f32x4*)(w_d + so);
        const f32x4 b = *(const f32x4*)(w_d + so + 4);
        #pragma unroll
        for (int j = 0; j < 4; ++j) { o[j] = f2bf(a[j]); o[4 + j] = f2bf(b[j]); }
      } else {
        #pragma unroll
        for (int j = 0; j < 8; ++j) o[j] = 0;
      }
      *(bf16x8*)(wdb + i * 8) = o;
    }
    return;
  }

  // ---- gate for token t (+ fused x->bf16)
  const int t = b4 * 2 + (r4 - 2);
  const float* xr = x + (size_t)t * D_MODEL;
  {
    short* xbr = xb + (size_t)t * D_MODEL;
    for (int i8 = tid; i8 < D_MODEL / 8; i8 += 256) {
      const f32x4 a = *(const f32x4*)(xr + i8 * 8);
      const f32x4 b = *(const f32x4*)(xr + i8 * 8 + 4);
      bf16x8 o;
      #pragma unroll
      for (int j = 0; j < 4; ++j) { o[j] = f2bf(a[j]); o[4 + j] = f2bf(b[j]); }
      *(bf16x8*)(xbr + i8 * 8) = o;
    }
  }

  double acc[NEXP];
  #pragma unroll
  for (int e = 0; e < NEXP; ++e) acc[e] = 0.0;

  for (int i = tid; i < D_MODEL; i += 256) {
    const float xv = xr[i];
    const f32x4* w = (const f32x4*)(wg + (size_t)i * NEXP);
    #pragma unroll
    for (int q = 0; q < 4; ++q) {
      const f32x4 wv = w[q];
      #pragma unroll
      for (int j = 0; j < 4; ++j) acc[q * 4 + j] += (double)xv * (double)wv[j];
    }
  }

  #pragma unroll
  for (int e = 0; e < NEXP; ++e) {
    double v = acc[e];
    #pragma unroll
    for (int off = 32; off > 0; off >>= 1) v += __shfl_xor(v, off, 64);
    acc[e] = v;
  }

  const int lane = tid & 63, wid = tid >> 6;
  if (lane == 0) {
    #pragma unroll
    for (int e = 0; e < NEXP; ++e) red[wid][e] = acc[e];
  }
  __syncthreads();

  if (tid == 0) {
    float lg[NEXP];
    #pragma unroll
    for (int e = 0; e < NEXP; ++e)
      lg[e] = (float)(red[0][e] + red[1][e] + red[2][e] + red[3][e]);

    int   idx[NSEL];
    float val[NSEL];
    unsigned used = 0;
    for (int k = 0; k < NSEL; ++k) {
      float best = -3.4e38f; int bi = 0;
      for (int e = 0; e < NEXP; ++e)
        if (!((used >> e) & 1u) && lg[e] > best) { best = lg[e]; bi = e; }
      idx[k] = bi; val[k] = best; used |= 1u << bi;
    }
    const float m = val[0];
    float ex[NSEL], s = 0.f;
    for (int k = 0; k < NSEL; ++k) { ex[k] = expf(val[k] - m); s += ex[k]; }
    for (int k = 0; k < NSEL; ++k) {
      const float sc = ex[k] / s;
      const int e = idx[k];
      const int pos = atomicAdd(&counts[e], 1);
      pair_tok[e * NTOK + pos]  = t;
      pair_scr[e * NTOK + pos]  = sc;
      pair_rank[e * NTOK + pos] = k;
      atomicAdd(&importance[e], sc);
    }
  }
}

// ---------------------------------------------------------------- scan + balance loss
__global__ void scan_loss_kernel(const int* __restrict__ counts,
                                 const float* __restrict__ importance,
                                 int* __restrict__ offs, float* __restrict__ loss_out)
{
  if (threadIdx.x != 0 || blockIdx.x != 0) return;
  int   c[NEXP]; float im[NEXP];
  for (int e = 0; e < NEXP; ++e) { c[e] = counts[e]; im[e] = importance[e]; }
  int o = 0;
  for (int e = 0; e < NEXP; ++e) { offs[e] = o; o += c[e]; }
  float mi = 0.f, ml = 0.f;
  for (int e = 0; e < NEXP; ++e) { mi += im[e]; ml += (float)c[e]; }
  mi /= NEXP; ml /= NEXP;
  float vi = 0.f, vl = 0.f;
  for (int e = 0; e < NEXP; ++e) {
    vi += (im[e] - mi) * (im[e] - mi);
    vl += ((float)c[e] - ml) * ((float)c[e] - ml);
  }
  vi /= (NEXP - 1); vl /= (NEXP - 1);
  const float loss = 0.01f * (vi / (mi * mi + 1e-10f) + vl / (ml * ml + 1e-10f));
  *loss_out = loss;
}

// ================================================================ stage 1: BM=128, BN=64(g)+64(u), BK=32.
// Asymmetric prefetch: A (L3-hot x) 2-buf depth-1; G/U (HBM stream) 3-buf
// depth-2 with counted vmcnt. LDS 40KB -> 4 blocks/CU preserved.
__global__ __launch_bounds__(256, 4) void stage1b_kernel(
    const short* __restrict__ xb, const short* __restrict__ wgb,
    const short* __restrict__ wub, const int* __restrict__ counts,
    const int* __restrict__ offs, const int* __restrict__ pair_tok,
    const float* __restrict__ pair_scr, short* __restrict__ H)
{
  const int bid = blockIdx.x;
  const int ht  = bid >> 9;            // 0..10 (slowest)
  const int q   = bid & 511;
  const int xcd = q & 7;
  const int idx = q >> 3;
  const int e   = xcd * 2 + (idx & 1);
  const int mt  = idx >> 1;

  const int n_e = counts[e];
  const int m0  = mt * 128;
  if (m0 >= n_e) return;
  const int h0  = ht * 64;

  __shared__ short ldsA[2][128 * 32];
  __shared__ short ldsG[3][64 * 32];
  __shared__ short ldsU[3][64 * 32];

  const int tid  = threadIdx.x;
  const int lane = tid & 63;
  const int wid  = tid >> 6;

  const short* srcA[2]; const short* srcG; const short* srcU;
  #pragma unroll
  for (int i = 0; i < 2; ++i) {
    const int c    = wid * 2 + i;
    const int row  = 16 * c + (lane >> 2);
    const int slot = (lane & 3) ^ ((row >> 1) & 3);
    int r = m0 + row; if (r >= n_e) r = n_e - 1;
    const int tok = pair_tok[e * NTOK + r];
    srcA[i] = xb + (size_t)tok * D_MODEL + slot * 8;
  }
  {
    const int row  = 16 * wid + (lane >> 2);
    const int slot = (lane & 3) ^ ((row >> 1) & 3);
    const size_t rb = ((size_t)e * HIDP + h0 + row) * D_MODEL + slot * 8;
    srcG = wgb + rb;
    srcU = wub + rb;
  }

  const int wm = wid >> 1, wn = wid & 1;
  const int fr = lane & 15, fs = lane >> 4;
  const int so = (fs ^ ((fr >> 1) & 3)) * 8;

  f32x4 accg[4][2], accu[4][2];
  #pragma unroll
  for (int fi = 0; fi < 4; ++fi)
    #pragma unroll
    for (int fj = 0; fj < 2; ++fj) {
      accg[fi][fj] = f32x4{0.f, 0.f, 0.f, 0.f};
      accu[fi][fj] = f32x4{0.f, 0.f, 0.f, 0.f};
    }

  auto stageA = [&](int kt, int b) {          // 2 loads
    const int ko = kt * 32;
    #pragma unroll
    for (int i = 0; i < 2; ++i)
      gload16(srcA[i] + ko, &ldsA[b][(wid * 2 + i) * 512]);
  };
  auto stageGU = [&](int kt, int b) {         // 2 loads
    const int ko = kt * 32;
    gload16(srcG + ko, &ldsG[b][wid * 512]);
    gload16(srcU + ko, &ldsU[b][wid * 512]);
  };

  auto compute = [&](int ab, int gub) {
    const short* Ab = ldsA[ab]; const short* Gb = ldsG[gub]; const short* Ub = ldsU[gub];
    bf16x8 af[4], bg[2], bu[2];
    #pragma unroll
    for (int fi = 0; fi < 4; ++fi)
      af[fi] = *(const bf16x8*)&Ab[(wm * 64 + fi * 16 + fr) * 32 + so];
    #pragma unroll
    for (int fj = 0; fj < 2; ++fj) {
      bg[fj] = *(const bf16x8*)&Gb[(wn * 32 + fj * 16 + fr) * 32 + so];
      bu[fj] = *(const bf16x8*)&Ub[(wn * 32 + fj * 16 + fr) * 32 + so];
    }
    #pragma unroll
    for (int fi = 0; fi < 4; ++fi)
      #pragma unroll
      for (int fj = 0; fj < 2; ++fj) {
        accg[fi][fj] = __builtin_amdgcn_mfma_f32_16x16x32_bf16(af[fi], bg[fj], accg[fi][fj], 0, 0, 0);
        accu[fi][fj] = __builtin_amdgcn_mfma_f32_16x16x32_bf16(af[fi], bu[fj], accu[fi][fj], 0, 0, 0);
      }
  };

  const int KT = D_MODEL / 32;  // 128
  // prologue FIFO: GU(0), GU(1), A(0)
  stageGU(0, 0); stageGU(1, 1); stageA(0, 0);
  int gub = 0;                   // = kt % 3
  for (int kt = 0; kt < KT; ++kt) {
    const int ab = kt & 1;
    __builtin_amdgcn_s_barrier();               // compute(kt-1) done: bufs free
    __builtin_amdgcn_sched_barrier(0);
    if (kt + 1 < KT) stageA(kt + 1, (kt + 1) & 1);
    if (kt + 2 < KT) { int t3 = gub + 2; if (t3 >= 3) t3 -= 3; stageGU(kt + 2, t3); }
    // FIFO: GU(kt),A(kt) oldest -> retire them; leave GU(kt+1),A(kt+1),GU(kt+2)
    if (kt + 2 < KT)      { VMCNT(6); }
    else if (kt + 1 < KT) { VMCNT(4); }
    else                  { VMCNT(0); }
    __builtin_amdgcn_s_barrier();               // all waves' tile-kt data visible
    __builtin_amdgcn_sched_barrier(0);
    compute(ab, gub);
    ++gub; if (gub == 3) gub = 0;
  }

  const int offs_e = offs[e];
  #pragma unroll
  for (int fi = 0; fi < 4; ++fi)
    #pragma unroll
    for (int fj = 0; fj < 2; ++fj)
      #pragma unroll
      for (int j = 0; j < 4; ++j) {
        const int r = m0 + wm * 64 + fi * 16 + fs * 4 + j;
        if (r < n_e) {
          const int c = h0 + wn * 32 + fj * 16 + fr;
          const float sc = pair_scr[e * NTOK + r];
          const float g  = accg[fi][fj][j];
          const float u  = accu[fi][fj][j];
          const float hv = (g / (1.f + expf(-g))) * u * sc;
          H[(size_t)(offs_e + r) * HIDP + c] = f2bf(hv);
        }
      }
}

// ================================================================ stage 2 (store path): BM=128, BN=256, BK=32, 8 waves.
// Asymmetric prefetch: A (H, L3-hot) 2-buf; B (wd, HBM stream) 3-buf depth-2.
__global__ __launch_bounds__(512, 4) void stage2s_kernel(
    const short* __restrict__ H, const short* __restrict__ wdb,
    const int* __restrict__ counts, const int* __restrict__ offs,
    const int* __restrict__ pair_tok, const int* __restrict__ pair_rank,
    short* __restrict__ Yk)
{
  const int bid = blockIdx.x;
  const int dt  = bid >> 9;            // 0..15 (slowest)
  const int q   = bid & 511;
  const int xcd = q & 7;
  const int idx = q >> 3;
  const int e   = xcd * 2 + (idx & 1);
  const int mt  = idx >> 1;            // 0..31

  const int n_e = counts[e];
  const int m0  = mt * 128;
  if (m0 >= n_e) return;
  const int d0  = dt * 256;

  __shared__ short ldsA[2][128 * 32];
  __shared__ short ldsB[3][256 * 32];

  const int tid  = threadIdx.x;
  const int lane = tid & 63;
  const int wv   = tid >> 6;           // 0..7
  const int offs_e = offs[e];

  const short* srcA; const short* srcB[2];
  {
    const int row  = tid >> 2;                     // 0..127
    const int slot = (tid & 3) ^ ((row >> 1) & 3);
    int r = m0 + row; if (r >= n_e) r = n_e - 1;
    srcA = H + (size_t)(offs_e + r) * HIDP + slot * 8;
  }
  #pragma unroll
  for (int i = 0; i < 2; ++i) {
    const int row  = i * 128 + (tid >> 2);         // 0..255
    const int slot = (tid & 3) ^ ((row >> 1) & 3);
    srcB[i] = wdb + ((size_t)e * D_MODEL + d0 + row) * HIDP + slot * 8;
  }

  const int wm = wv >> 2, wn = wv & 3;  // 2 x 4 waves, each 64x64
  const int fr = lane & 15, fs = lane >> 4;
  const int so = (fs ^ ((fr >> 1) & 3)) * 8;

  f32x4 acc[4][4];
  #pragma unroll
  for (int fi = 0; fi < 4; ++fi)
    #pragma unroll
    for (int fj = 0; fj < 4; ++fj) acc[fi][fj] = f32x4{0.f, 0.f, 0.f, 0.f};

  auto stageA = [&](int kt, int b) {    // 1 load
    gload16(srcA + kt * 32, &ldsA[b][wv * 512]);
  };
  auto stageB = [&](int kt, int b) {    // 2 loads
    const int ko = kt * 32;
    #pragma unroll
    for (int i = 0; i < 2; ++i)
      gload16(srcB[i] + ko, &ldsB[b][i * 4096 + wv * 512]);
  };

  auto compute = [&](int ab, int bb_) {
    const short* Ab = ldsA[ab]; const short* Bb = ldsB[bb_];
    bf16x8 af[4], bb[4];
    #pragma unroll
    for (int fi = 0; fi < 4; ++fi)
      af[fi] = *(const bf16x8*)&Ab[(wm * 64 + fi * 16 + fr) * 32 + so];
    #pragma unroll
    for (int fj = 0; fj < 4; ++fj)
      bb[fj] = *(const bf16x8*)&Bb[(wn * 64 + fj * 16 + fr) * 32 + so];
    #pragma unroll
    for (int fi = 0; fi < 4; ++fi)
      #pragma unroll
      for (int fj = 0; fj < 4; ++fj)
        acc[fi][fj] = __builtin_amdgcn_mfma_f32_16x16x32_bf16(af[fi], bb[fj], acc[fi][fj], 0, 0, 0);
  };

  const int KT = HIDP / 32;  // 22
  stageB(0, 0); stageB(1, 1); stageA(0, 0);
  int bb = 0;
  for (int kt = 0; kt < KT; ++kt) {
    const int ab = kt & 1;
    __builtin_amdgcn_s_barrier();
    __builtin_amdgcn_sched_barrier(0);
    if (kt + 1 < KT) stageA(kt + 1, (kt + 1) & 1);
    if (kt + 2 < KT) { int t3 = bb + 2; if (t3 >= 3) t3 -= 3; stageB(kt + 2, t3); }
    // FIFO: B(kt)[2],A(kt)[1] retire; leave B(kt+1)[2],A(kt+1)[1],B(kt+2)[2]
    if (kt + 2 < KT)      { VMCNT(5); }
    else if (kt + 1 < KT) { VMCNT(3); }
    else                  { VMCNT(0); }
    __builtin_amdgcn_s_barrier();
    __builtin_amdgcn_sched_barrier(0);
    compute(ab, bb);
    ++bb; if (bb == 3) bb = 0;
  }

  #pragma unroll
  for (int fi = 0; fi < 4; ++fi)
    #pragma unroll
    for (int j = 0; j < 4; ++j) {
      const int r = m0 + wm * 64 + fi * 16 + fs * 4 + j;
      if (r < n_e) {
        const int tok = pair_tok[e * NTOK + r];
        const int rk  = pair_rank[e * NTOK + r];
        short* yr = Yk + ((size_t)rk * NTOK + tok) * D_MODEL + d0 + wn * 64 + fr;
        #pragma unroll
        for (int fj = 0; fj < 4; ++fj)
          yr[fj * 16] = f2bf(acc[fi][fj][j]);
      }
    }
}

// reduce 4 bf16 rank planes -> f32 y (8 elems/thread)
__global__ __launch_bounds__(256) void reduce_y_kernel(const short* __restrict__ Yk,
                                                       float* __restrict__ y) {
  const size_t i = ((size_t)blockIdx.x * 256 + threadIdx.x) * 8;
  const size_t P = (size_t)NTOK * D_MODEL;
  const bf16x8 a = *(const bf16x8*)(Yk + i);
  const bf16x8 b = *(const bf16x8*)(Yk + P + i);
  const bf16x8 c = *(const bf16x8*)(Yk + 2 * P + i);
  const bf16x8 d = *(const bf16x8*)(Yk + 3 * P + i);
  f32x4 lo, hi;
  #pragma unroll
  for (int j = 0; j < 4; ++j) {
    lo[j] = bf2f(a[j]) + bf2f(b[j]) + bf2f(c[j]) + bf2f(d[j]);
    hi[j] = bf2f(a[4 + j]) + bf2f(b[4 + j]) + bf2f(c[4 + j]) + bf2f(d[4 + j]);
  }
  *(f32x4*)(y + i)     = lo;
  *(f32x4*)(y + i + 4) = hi;
}

// ================================================================ stage 2 (atomic fallback)
__global__ __launch_bounds__(256, 4) void stage2a_kernel(
    const short* __restrict__ H, const short* __restrict__ wdb,
    const int* __restrict__ counts, const int* __restrict__ offs,
    const int* __restrict__ pair_tok, float* __restrict__ y)
{
  const int bid = blockIdx.x;
  const int dt  = bid >> 9;
  const int q   = bid & 511;
  const int xcd = q & 7;
  const int idx = q >> 3;
  const int e   = xcd * 2 + (idx & 1);
  const int mt  = idx >> 1;

  const int n_e = counts[e];
  const int m0  = mt * 128;
  if (m0 >= n_e) return;
  const int d0  = dt * 128;

  __shared__ short ldsA[2][128 * 32];
  __shared__ short ldsB[2][128 * 32];

  const int tid  = threadIdx.x;
  const int lane = tid & 63;
  const int wid  = tid >> 6;
  const int offs_e = offs[e];

  const short* srcA[2]; const short* srcB[2];
  #pragma unroll
  for (int i = 0; i < 2; ++i) {
    const int c    = wid * 2 + i;
    const int row  = 16 * c + (lane >> 2);
    const int slot = (lane & 3) ^ ((row >> 1) & 3);
    int r = m0 + row; if (r >= n_e) r = n_e - 1;
    srcA[i] = H + (size_t)(offs_e + r) * HIDP + slot * 8;
    srcB[i] = wdb + ((size_t)e * D_MODEL + d0 + row) * HIDP + slot * 8;
  }

  const int wm = wid >> 1, wn = wid & 1;
  const int fr = lane & 15, fs = lane >> 4;
  const int so = (fs ^ ((fr >> 1) & 3)) * 8;

  f32x4 acc[4][4];
  #pragma unroll
  for (int fi = 0; fi < 4; ++fi)
    #pragma unroll
    for (int fj = 0; fj < 4; ++fj) acc[fi][fj] = f32x4{0.f, 0.f, 0.f, 0.f};

  auto stage = [&](int kt, int b) {
    const int ko = kt * 32;
    #pragma unroll
    for (int i = 0; i < 2; ++i) {
      gload16(srcA[i] + ko, &ldsA[b][(wid * 2 + i) * 512]);
      gload16(srcB[i] + ko, &ldsB[b][(wid * 2 + i) * 512]);
    }
  };

  auto compute = [&](int b) {
    const short* Ab = ldsA[b]; const short* Bb = ldsB[b];
    bf16x8 af[4], bb[4];
    #pragma unroll
    for (int fi = 0; fi < 4; ++fi)
      af[fi] = *(const bf16x8*)&Ab[(wm * 64 + fi * 16 + fr) * 32 + so];
    #pragma unroll
    for (int fj = 0; fj < 4; ++fj)
      bb[fj] = *(const bf16x8*)&Bb[(wn * 64 + fj * 16 + fr) * 32 + so];
    #pragma unroll
    for (int fi = 0; fi < 4; ++fi)
      #pragma unroll
      for (int fj = 0; fj < 4; ++fj)
        acc[fi][fj] = __builtin_amdgcn_mfma_f32_16x16x32_bf16(af[fi], bb[fj], acc[fi][fj], 0, 0, 0);
  };

  const int KT = HIDP / 32;
  stage(0, 0);
  for (int kt = 0; kt < KT; ++kt) {
    const int cur = kt & 1;
    __syncthreads();
    if (kt + 1 < KT) stage(kt + 1, cur ^ 1);
    compute(cur);
  }

  #pragma unroll
  for (int fi = 0; fi < 4; ++fi)
    #pragma unroll
    for (int j = 0; j < 4; ++j) {
      const int r = m0 + wm * 64 + fi * 16 + fs * 4 + j;
      if (r < n_e) {
        const int tok = pair_tok[e * NTOK + r];
        float* yr = y + (size_t)tok * D_MODEL + d0 + wn * 64 + fr;
        #pragma unroll
        for (int fj = 0; fj < 4; ++fj)
          atomicAdd(yr + fj * 16, acc[fi][fj][j]);
      }
    }
}

// ---------------------------------------------------------------- launch
extern "C" void kernel_launch(void* const* d_in, const int* in_sizes, int n_in,
                              void* d_out, int out_size, void* d_ws, size_t ws_size,
                              hipStream_t stream) {
  const float* x     = (const float*)d_in[0];
  const float* wgate = (const float*)d_in[1];
  const float* w_g   = (const float*)d_in[2];
  const float* w_u   = (const float*)d_in[3];
  const float* w_d   = (const float*)d_in[4];

  float* y        = (float*)d_out;
  float* loss_out = y + (size_t)NTOK * D_MODEL;

  char* ws = (char*)d_ws;
  int*   counts     = (int*)ws;
  int*   offs       = counts + 16;
  float* importance = (float*)(counts + 32);
  int*   pair_tok   = (int*)(ws + 256);
  float* pair_scr   = (float*)(ws + 256 + (size_t)NEXP * NTOK * 4);
  int*   pair_rank  = (int*)(ws + 256 + (size_t)2 * NEXP * NTOK * 4);
  short* H          = (short*)(ws + 256 + (size_t)3 * NEXP * NTOK * 4);

  const size_t H_BYTES = (size_t)NTOK * NSEL * HIDP * 2;
  short* xbuf = (short*)((char*)H + H_BYTES);
  short* wgb  = xbuf + (size_t)NTOK * D_MODEL;
  short* wub  = wgb + (size_t)NEXP * HIDP * D_MODEL;
  short* wdb  = wub + (size_t)NEXP * HIDP * D_MODEL;
  short* Yk   = wdb + (size_t)NEXP * HIDP * D_MODEL;

  const size_t NEED_STORE = ((char*)(Yk + (size_t)NSEL * NTOK * D_MODEL)) - ws;
  const bool store_path = ws_size >= NEED_STORE;

  hipLaunchKernelGGL(zero_meta_kernel, dim3(1), dim3(64), 0, stream, counts, importance);
  hipLaunchKernelGGL(gate_conv_kernel, dim3(8192), dim3(256), 0, stream,
                     x, wgate, counts, importance, pair_tok, pair_scr, pair_rank, xbuf,
                     w_g, w_u, wgb, wub, w_d, wdb);
  hipLaunchKernelGGL(scan_loss_kernel, dim3(1), dim3(64), 0, stream,
                     counts, importance, offs, loss_out);
  hipLaunchKernelGGL(stage1b_kernel, dim3(11 * 512), dim3(256), 0, stream,
                     xbuf, wgb, wub, counts, offs, pair_tok, pair_scr, H);

  if (store_path) {
    hipLaunchKernelGGL(stage2s_kernel, dim3(16 * 512), dim3(512), 0, stream,
                       H, wdb, counts, offs, pair_tok, pair_rank, Yk);
    hipLaunchKernelGGL(reduce_y_kernel, dim3(NTOK * D_MODEL / 8 / 256), dim3(256), 0, stream,
                       Yk, y);
  } else {
    hipLaunchKernelGGL(zero_y_kernel, dim3(16384), dim3(256), 0, stream, y);
    hipLaunchKernelGGL(stage2a_kernel, dim3(32 * 512), dim3(256), 0, stream,
                       H, wdb, counts, offs, pair_tok, y);
  }
}

// Round 16
// 748.246 us; speedup vs baseline: 1.0232x; 1.0232x over previous
//
#include <hip/hip_runtime.h>
#include <hip/hip_bf16.h>

#define D_MODEL 4096
#define NEXP    16
#define HID     688
#define HIDP    704
#define NSEL    4
#define NTOK    4096

typedef __attribute__((ext_vector_type(4))) float  f32x4;
typedef __attribute__((ext_vector_type(8))) short  bf16x8;

__device__ __forceinline__ short f2bf(float f) {
  __hip_bfloat16 h = __float2bfloat16(f);
  return __builtin_bit_cast(short, h);
}

__device__ __forceinline__ float bf2f(short s) {
  const unsigned u = ((unsigned)(unsigned short)s) << 16;
  return __builtin_bit_cast(float, u);
}

__device__ __forceinline__ void gload16(const void* g, void* l) {
  __builtin_amdgcn_global_load_lds(
      (const __attribute__((address_space(1))) unsigned int*)g,
      (__attribute__((address_space(3))) unsigned int*)l, 16, 0, 0);
}

// ---------------------------------------------------------------- zero init
__global__ void zero_meta_kernel(int* counts, float* importance) {
  const int tid = threadIdx.x;
  if (tid < NEXP) counts[tid] = 0;
  else if (tid < 2 * NEXP) importance[tid - NEXP] = 0.f;
}

__global__ void zero_y_kernel(float* __restrict__ y) {
  const size_t i = (size_t)blockIdx.x * 256 + threadIdx.x;
  *(f32x4*)(y + i * 4) = f32x4{0.f, 0.f, 0.f, 0.f};
}

// ---------------------------------------------------------------- fused gate + conv_wgu + conv_wd (all BW-bound; interleaved)
// bid&3: 0 -> conv_wgu (2048 blocks), 1 -> conv_wd (2048), 2|3 -> gate (4096)
__global__ __launch_bounds__(256) void gate_conv_kernel(
    const float* __restrict__ x, const float* __restrict__ wg,
    int* __restrict__ counts, float* __restrict__ importance,
    int* __restrict__ pair_tok, float* __restrict__ pair_scr,
    int* __restrict__ pair_rank, short* __restrict__ xb,
    const float* __restrict__ w_g, const float* __restrict__ w_u,
    short* __restrict__ gb, short* __restrict__ ub,
    const float* __restrict__ w_d, short* __restrict__ wdb)
{
  __shared__ double red[4][NEXP];
  const int tid = threadIdx.x;
  const int r4  = blockIdx.x & 3;
  const int b4  = blockIdx.x >> 2;

  if (r4 == 0) {
    const size_t stride = (size_t)2048 * 256;
    const size_t n8 = (size_t)NEXP * HIDP * (D_MODEL / 8);
    for (size_t i = (size_t)b4 * 256 + tid; i < n8; i += stride) {
      const int c8  = (int)(i & 511);
      const int row = (int)((i >> 9) % HIDP);
      const int e   = (int)(i / (512 * HIDP));
      bf16x8 og, ou;
      if (row < HID) {
        const size_t so = ((size_t)e * HID + row) * D_MODEL + (size_t)c8 * 8;
        const f32x4 ga  = *(const f32x4*)(w_g + so);
        const f32x4 gbv = *(const f32x4*)(w_g + so + 4);
        const f32x4 ua  = *(const f32x4*)(w_u + so);
        const f32x4 ubv = *(const f32x4*)(w_u + so + 4);
        #pragma unroll
        for (int j = 0; j < 4; ++j) {
          og[j] = f2bf(ga[j]); og[4 + j] = f2bf(gbv[j]);
          ou[j] = f2bf(ua[j]); ou[4 + j] = f2bf(ubv[j]);
        }
      } else {
        #pragma unroll
        for (int j = 0; j < 8; ++j) { og[j] = 0; ou[j] = 0; }
      }
      *(bf16x8*)(gb + i * 8) = og;
      *(bf16x8*)(ub + i * 8) = ou;
    }
    return;
  }

  if (r4 == 1) {
    const size_t stride = (size_t)2048 * 256;
    const size_t n8 = (size_t)NEXP * D_MODEL * (HIDP / 8);
    for (size_t i = (size_t)b4 * 256 + tid; i < n8; i += stride) {
      const int c8  = (int)(i % 88);
      const int row = (int)((i / 88) & (D_MODEL - 1));
      const int e   = (int)(i / (88 * D_MODEL));
      bf16x8 o;
      if (c8 < 86) {
        const size_t so = ((size_t)e * D_MODEL + row) * HID + (size_t)c8 * 8;
        const f32x4 a = *(const f32x4*)(w_d + so);
        const f32x4 b = *(const f32x4*)(w_d + so + 4);
        #pragma unroll
        for (int j = 0; j < 4; ++j) { o[j] = f2bf(a[j]); o[4 + j] = f2bf(b[j]); }
      } else {
        #pragma unroll
        for (int j = 0; j < 8; ++j) o[j] = 0;
      }
      *(bf16x8*)(wdb + i * 8) = o;
    }
    return;
  }

  // ---- gate for token t (+ fused x->bf16)
  const int t = b4 * 2 + (r4 - 2);
  const float* xr = x + (size_t)t * D_MODEL;
  {
    short* xbr = xb + (size_t)t * D_MODEL;
    for (int i8 = tid; i8 < D_MODEL / 8; i8 += 256) {
      const f32x4 a = *(const f32x4*)(xr + i8 * 8);
      const f32x4 b = *(const f32x4*)(xr + i8 * 8 + 4);
      bf16x8 o;
      #pragma unroll
      for (int j = 0; j < 4; ++j) { o[j] = f2bf(a[j]); o[4 + j] = f2bf(b[j]); }
      *(bf16x8*)(xbr + i8 * 8) = o;
    }
  }

  double acc[NEXP];
  #pragma unroll
  for (int e = 0; e < NEXP; ++e) acc[e] = 0.0;

  for (int i = tid; i < D_MODEL; i += 256) {
    const float xv = xr[i];
    const f32x4* w = (const f32x4*)(wg + (size_t)i * NEXP);
    #pragma unroll
    for (int q = 0; q < 4; ++q) {
      const f32x4 wv = w[q];
      #pragma unroll
      for (int j = 0; j < 4; ++j) acc[q * 4 + j] += (double)xv * (double)wv[j];
    }
  }

  #pragma unroll
  for (int e = 0; e < NEXP; ++e) {
    double v = acc[e];
    #pragma unroll
    for (int off = 32; off > 0; off >>= 1) v += __shfl_xor(v, off, 64);
    acc[e] = v;
  }

  const int lane = tid & 63, wid = tid >> 6;
  if (lane == 0) {
    #pragma unroll
    for (int e = 0; e < NEXP; ++e) red[wid][e] = acc[e];
  }
  __syncthreads();

  if (tid == 0) {
    float lg[NEXP];
    #pragma unroll
    for (int e = 0; e < NEXP; ++e)
      lg[e] = (float)(red[0][e] + red[1][e] + red[2][e] + red[3][e]);

    int   idx[NSEL];
    float val[NSEL];
    unsigned used = 0;
    for (int k = 0; k < NSEL; ++k) {
      float best = -3.4e38f; int bi = 0;
      for (int e = 0; e < NEXP; ++e)
        if (!((used >> e) & 1u) && lg[e] > best) { best = lg[e]; bi = e; }
      idx[k] = bi; val[k] = best; used |= 1u << bi;
    }
    const float m = val[0];
    float ex[NSEL], s = 0.f;
    for (int k = 0; k < NSEL; ++k) { ex[k] = expf(val[k] - m); s += ex[k]; }
    for (int k = 0; k < NSEL; ++k) {
      const float sc = ex[k] / s;
      const int e = idx[k];
      const int pos = atomicAdd(&counts[e], 1);
      pair_tok[e * NTOK + pos]  = t;
      pair_scr[e * NTOK + pos]  = sc;
      pair_rank[e * NTOK + pos] = k;
      atomicAdd(&importance[e], sc);
    }
  }
}

// ---------------------------------------------------------------- scan + balance loss
__global__ void scan_loss_kernel(const int* __restrict__ counts,
                                 const float* __restrict__ importance,
                                 int* __restrict__ offs, float* __restrict__ loss_out)
{
  if (threadIdx.x != 0 || blockIdx.x != 0) return;
  int   c[NEXP]; float im[NEXP];
  for (int e = 0; e < NEXP; ++e) { c[e] = counts[e]; im[e] = importance[e]; }
  int o = 0;
  for (int e = 0; e < NEXP; ++e) { offs[e] = o; o += c[e]; }
  float mi = 0.f, ml = 0.f;
  for (int e = 0; e < NEXP; ++e) { mi += im[e]; ml += (float)c[e]; }
  mi /= NEXP; ml /= NEXP;
  float vi = 0.f, vl = 0.f;
  for (int e = 0; e < NEXP; ++e) {
    vi += (im[e] - mi) * (im[e] - mi);
    vl += ((float)c[e] - ml) * ((float)c[e] - ml);
  }
  vi /= (NEXP - 1); vl /= (NEXP - 1);
  const float loss = 0.01f * (vi / (mi * mi + 1e-10f) + vl / (ml * ml + 1e-10f));
  *loss_out = loss;
}

// ================================================================ stage 1 (best measured): BM=128, BN=64(g)+64(u), BK=32 dbuf
// ht slowest (weights stream once per round; x L3-absorbs re-reads).
__global__ __launch_bounds__(256, 4) void stage1b_kernel(
    const short* __restrict__ xb, const short* __restrict__ wgb,
    const short* __restrict__ wub, const int* __restrict__ counts,
    const int* __restrict__ offs, const int* __restrict__ pair_tok,
    const float* __restrict__ pair_scr, short* __restrict__ H)
{
  const int bid = blockIdx.x;
  const int ht  = bid >> 9;            // 0..10 (slowest)
  const int q   = bid & 511;
  const int xcd = q & 7;
  const int idx = q >> 3;
  const int e   = xcd * 2 + (idx & 1);
  const int mt  = idx >> 1;

  const int n_e = counts[e];
  const int m0  = mt * 128;
  if (m0 >= n_e) return;
  const int h0  = ht * 64;

  __shared__ short ldsA[2][128 * 32];
  __shared__ short ldsG[2][64 * 32];
  __shared__ short ldsU[2][64 * 32];

  const int tid  = threadIdx.x;
  const int lane = tid & 63;
  const int wid  = tid >> 6;

  const short* srcA[2]; const short* srcG; const short* srcU;
  #pragma unroll
  for (int i = 0; i < 2; ++i) {
    const int c    = wid * 2 + i;
    const int row  = 16 * c + (lane >> 2);
    const int slot = (lane & 3) ^ ((row >> 1) & 3);
    int r = m0 + row; if (r >= n_e) r = n_e - 1;
    const int tok = pair_tok[e * NTOK + r];
    srcA[i] = xb + (size_t)tok * D_MODEL + slot * 8;
  }
  {
    const int row  = 16 * wid + (lane >> 2);
    const int slot = (lane & 3) ^ ((row >> 1) & 3);
    const size_t rb = ((size_t)e * HIDP + h0 + row) * D_MODEL + slot * 8;
    srcG = wgb + rb;
    srcU = wub + rb;
  }

  const int wm = wid >> 1, wn = wid & 1;
  const int fr = lane & 15, fs = lane >> 4;
  const int so = (fs ^ ((fr >> 1) & 3)) * 8;

  f32x4 accg[4][2], accu[4][2];
  #pragma unroll
  for (int fi = 0; fi < 4; ++fi)
    #pragma unroll
    for (int fj = 0; fj < 2; ++fj) {
      accg[fi][fj] = f32x4{0.f, 0.f, 0.f, 0.f};
      accu[fi][fj] = f32x4{0.f, 0.f, 0.f, 0.f};
    }

  auto stage = [&](int kt, int b) {
    const int ko = kt * 32;
    #pragma unroll
    for (int i = 0; i < 2; ++i)
      gload16(srcA[i] + ko, &ldsA[b][(wid * 2 + i) * 512]);
    gload16(srcG + ko, &ldsG[b][wid * 512]);
    gload16(srcU + ko, &ldsU[b][wid * 512]);
  };

  auto compute = [&](int b) {
    const short* Ab = ldsA[b]; const short* Gb = ldsG[b]; const short* Ub = ldsU[b];
    bf16x8 af[4], bg[2], bu[2];
    #pragma unroll
    for (int fi = 0; fi < 4; ++fi)
      af[fi] = *(const bf16x8*)&Ab[(wm * 64 + fi * 16 + fr) * 32 + so];
    #pragma unroll
    for (int fj = 0; fj < 2; ++fj) {
      bg[fj] = *(const bf16x8*)&Gb[(wn * 32 + fj * 16 + fr) * 32 + so];
      bu[fj] = *(const bf16x8*)&Ub[(wn * 32 + fj * 16 + fr) * 32 + so];
    }
    #pragma unroll
    for (int fi = 0; fi < 4; ++fi)
      #pragma unroll
      for (int fj = 0; fj < 2; ++fj) {
        accg[fi][fj] = __builtin_amdgcn_mfma_f32_16x16x32_bf16(af[fi], bg[fj], accg[fi][fj], 0, 0, 0);
        accu[fi][fj] = __builtin_amdgcn_mfma_f32_16x16x32_bf16(af[fi], bu[fj], accu[fi][fj], 0, 0, 0);
      }
  };

  const int KT = D_MODEL / 32;  // 128
  stage(0, 0);
  for (int kt = 0; kt < KT; ++kt) {
    const int cur = kt & 1;
    __syncthreads();
    if (kt + 1 < KT) stage(kt + 1, cur ^ 1);
    compute(cur);
  }

  const int offs_e = offs[e];
  #pragma unroll
  for (int fi = 0; fi < 4; ++fi)
    #pragma unroll
    for (int fj = 0; fj < 2; ++fj)
      #pragma unroll
      for (int j = 0; j < 4; ++j) {
        const int r = m0 + wm * 64 + fi * 16 + fs * 4 + j;
        if (r < n_e) {
          const int c = h0 + wn * 32 + fj * 16 + fr;
          const float sc = pair_scr[e * NTOK + r];
          const float g  = accg[fi][fj][j];
          const float u  = accu[fi][fj][j];
          const float hv = (g / (1.f + expf(-g))) * u * sc;
          H[(size_t)(offs_e + r) * HIDP + c] = f2bf(hv);
        }
      }
}

// ================================================================ stage 2 (store path): BM=128, BN=256, BK=32 dbuf, 8 waves
// dt slowest; -> bf16 rank planes Yk[k][t][d].
__global__ __launch_bounds__(512, 4) void stage2s_kernel(
    const short* __restrict__ H, const short* __restrict__ wdb,
    const int* __restrict__ counts, const int* __restrict__ offs,
    const int* __restrict__ pair_tok, const int* __restrict__ pair_rank,
    short* __restrict__ Yk)
{
  const int bid = blockIdx.x;
  const int dt  = bid >> 9;            // 0..15 (slowest)
  const int q   = bid & 511;
  const int xcd = q & 7;
  const int idx = q >> 3;
  const int e   = xcd * 2 + (idx & 1);
  const int mt  = idx >> 1;            // 0..31

  const int n_e = counts[e];
  const int m0  = mt * 128;
  if (m0 >= n_e) return;
  const int d0  = dt * 256;

  __shared__ short ldsA[2][128 * 32];
  __shared__ short ldsB[2][256 * 32];

  const int tid  = threadIdx.x;
  const int lane = tid & 63;
  const int wv   = tid >> 6;           // 0..7
  const int offs_e = offs[e];

  const short* srcA; const short* srcB[2];
  {
    const int row  = tid >> 2;                     // 0..127
    const int slot = (tid & 3) ^ ((row >> 1) & 3);
    int r = m0 + row; if (r >= n_e) r = n_e - 1;
    srcA = H + (size_t)(offs_e + r) * HIDP + slot * 8;
  }
  #pragma unroll
  for (int i = 0; i < 2; ++i) {
    const int row  = i * 128 + (tid >> 2);         // 0..255
    const int slot = (tid & 3) ^ ((row >> 1) & 3);
    srcB[i] = wdb + ((size_t)e * D_MODEL + d0 + row) * HIDP + slot * 8;
  }

  const int wm = wv >> 2, wn = wv & 3;  // 2 x 4 waves, each 64x64
  const int fr = lane & 15, fs = lane >> 4;
  const int so = (fs ^ ((fr >> 1) & 3)) * 8;

  f32x4 acc[4][4];
  #pragma unroll
  for (int fi = 0; fi < 4; ++fi)
    #pragma unroll
    for (int fj = 0; fj < 4; ++fj) acc[fi][fj] = f32x4{0.f, 0.f, 0.f, 0.f};

  auto stage = [&](int kt, int b) {     // 3 vmem ops / thread
    const int ko = kt * 32;
    gload16(srcA + ko, &ldsA[b][wv * 512]);
    #pragma unroll
    for (int i = 0; i < 2; ++i)
      gload16(srcB[i] + ko, &ldsB[b][i * 4096 + wv * 512]);
  };

  auto compute = [&](int b) {
    const short* Ab = ldsA[b]; const short* Bb = ldsB[b];
    bf16x8 af[4], bb[4];
    #pragma unroll
    for (int fi = 0; fi < 4; ++fi)
      af[fi] = *(const bf16x8*)&Ab[(wm * 64 + fi * 16 + fr) * 32 + so];
    #pragma unroll
    for (int fj = 0; fj < 4; ++fj)
      bb[fj] = *(const bf16x8*)&Bb[(wn * 64 + fj * 16 + fr) * 32 + so];
    #pragma unroll
    for (int fi = 0; fi < 4; ++fi)
      #pragma unroll
      for (int fj = 0; fj < 4; ++fj)
        acc[fi][fj] = __builtin_amdgcn_mfma_f32_16x16x32_bf16(af[fi], bb[fj], acc[fi][fj], 0, 0, 0);
  };

  const int KT = HIDP / 32;  // 22
  stage(0, 0);
  for (int kt = 0; kt < KT; ++kt) {
    const int cur = kt & 1;
    __syncthreads();
    if (kt + 1 < KT) stage(kt + 1, cur ^ 1);
    compute(cur);
  }

  #pragma unroll
  for (int fi = 0; fi < 4; ++fi)
    #pragma unroll
    for (int j = 0; j < 4; ++j) {
      const int r = m0 + wm * 64 + fi * 16 + fs * 4 + j;
      if (r < n_e) {
        const int tok = pair_tok[e * NTOK + r];
        const int rk  = pair_rank[e * NTOK + r];
        short* yr = Yk + ((size_t)rk * NTOK + tok) * D_MODEL + d0 + wn * 64 + fr;
        #pragma unroll
        for (int fj = 0; fj < 4; ++fj)
          yr[fj * 16] = f2bf(acc[fi][fj][j]);
      }
    }
}

// reduce 4 bf16 rank planes -> f32 y (8 elems/thread)
__global__ __launch_bounds__(256) void reduce_y_kernel(const short* __restrict__ Yk,
                                                       float* __restrict__ y) {
  const size_t i = ((size_t)blockIdx.x * 256 + threadIdx.x) * 8;
  const size_t P = (size_t)NTOK * D_MODEL;
  const bf16x8 a = *(const bf16x8*)(Yk + i);
  const bf16x8 b = *(const bf16x8*)(Yk + P + i);
  const bf16x8 c = *(const bf16x8*)(Yk + 2 * P + i);
  const bf16x8 d = *(const bf16x8*)(Yk + 3 * P + i);
  f32x4 lo, hi;
  #pragma unroll
  for (int j = 0; j < 4; ++j) {
    lo[j] = bf2f(a[j]) + bf2f(b[j]) + bf2f(c[j]) + bf2f(d[j]);
    hi[j] = bf2f(a[4 + j]) + bf2f(b[4 + j]) + bf2f(c[4 + j]) + bf2f(d[4 + j]);
  }
  *(f32x4*)(y + i)     = lo;
  *(f32x4*)(y + i + 4) = hi;
}

// ================================================================ stage 2 (atomic fallback)
__global__ __launch_bounds__(256, 4) void stage2a_kernel(
    const short* __restrict__ H, const short* __restrict__ wdb,
    const int* __restrict__ counts, const int* __restrict__ offs,
    const int* __restrict__ pair_tok, float* __restrict__ y)
{
  const int bid = blockIdx.x;
  const int dt  = bid >> 9;
  const int q   = bid & 511;
  const int xcd = q & 7;
  const int idx = q >> 3;
  const int e   = xcd * 2 + (idx & 1);
  const int mt  = idx >> 1;

  const int n_e = counts[e];
  const int m0  = mt * 128;
  if (m0 >= n_e) return;
  const int d0  = dt * 128;

  __shared__ short ldsA[2][128 * 32];
  __shared__ short ldsB[2][128 * 32];

  const int tid  = threadIdx.x;
  const int lane = tid & 63;
  const int wid  = tid >> 6;
  const int offs_e = offs[e];

  const short* srcA[2]; const short* srcB[2];
  #pragma unroll
  for (int i = 0; i < 2; ++i) {
    const int c    = wid * 2 + i;
    const int row  = 16 * c + (lane >> 2);
    const int slot = (lane & 3) ^ ((row >> 1) & 3);
    int r = m0 + row; if (r >= n_e) r = n_e - 1;
    srcA[i] = H + (size_t)(offs_e + r) * HIDP + slot * 8;
    srcB[i] = wdb + ((size_t)e * D_MODEL + d0 + row) * HIDP + slot * 8;
  }

  const int wm = wid >> 1, wn = wid & 1;
  const int fr = lane & 15, fs = lane >> 4;
  const int so = (fs ^ ((fr >> 1) & 3)) * 8;

  f32x4 acc[4][4];
  #pragma unroll
  for (int fi = 0; fi < 4; ++fi)
    #pragma unroll
    for (int fj = 0; fj < 4; ++fj) acc[fi][fj] = f32x4{0.f, 0.f, 0.f, 0.f};

  auto stage = [&](int kt, int b) {
    const int ko = kt * 32;
    #pragma unroll
    for (int i = 0; i < 2; ++i) {
      gload16(srcA[i] + ko, &ldsA[b][(wid * 2 + i) * 512]);
      gload16(srcB[i] + ko, &ldsB[b][(wid * 2 + i) * 512]);
    }
  };

  auto compute = [&](int b) {
    const short* Ab = ldsA[b]; const short* Bb = ldsB[b];
    bf16x8 af[4], bb[4];
    #pragma unroll
    for (int fi = 0; fi < 4; ++fi)
      af[fi] = *(const bf16x8*)&Ab[(wm * 64 + fi * 16 + fr) * 32 + so];
    #pragma unroll
    for (int fj = 0; fj < 4; ++fj)
      bb[fj] = *(const bf16x8*)&Bb[(wn * 64 + fj * 16 + fr) * 32 + so];
    #pragma unroll
    for (int fi = 0; fi < 4; ++fi)
      #pragma unroll
      for (int fj = 0; fj < 4; ++fj)
        acc[fi][fj] = __builtin_amdgcn_mfma_f32_16x16x32_bf16(af[fi], bb[fj], acc[fi][fj], 0, 0, 0);
  };

  const int KT = HIDP / 32;
  stage(0, 0);
  for (int kt = 0; kt < KT; ++kt) {
    const int cur = kt & 1;
    __syncthreads();
    if (kt + 1 < KT) stage(kt + 1, cur ^ 1);
    compute(cur);
  }

  #pragma unroll
  for (int fi = 0; fi < 4; ++fi)
    #pragma unroll
    for (int j = 0; j < 4; ++j) {
      const int r = m0 + wm * 64 + fi * 16 + fs * 4 + j;
      if (r < n_e) {
        const int tok = pair_tok[e * NTOK + r];
        float* yr = y + (size_t)tok * D_MODEL + d0 + wn * 64 + fr;
        #pragma unroll
        for (int fj = 0; fj < 4; ++fj)
          atomicAdd(yr + fj * 16, acc[fi][fj][j]);
      }
    }
}

// ---------------------------------------------------------------- launch
extern "C" void kernel_launch(void* const* d_in, const int* in_sizes, int n_in,
                              void* d_out, int out_size, void* d_ws, size_t ws_size,
                              hipStream_t stream) {
  const float* x     = (const float*)d_in[0];
  const float* wgate = (const float*)d_in[1];
  const float* w_g   = (const float*)d_in[2];
  const float* w_u   = (const float*)d_in[3];
  const float* w_d   = (const float*)d_in[4];

  float* y        = (float*)d_out;
  float* loss_out = y + (size_t)NTOK * D_MODEL;

  char* ws = (char*)d_ws;
  int*   counts     = (int*)ws;
  int*   offs       = counts + 16;
  float* importance = (float*)(counts + 32);
  int*   pair_tok   = (int*)(ws + 256);
  float* pair_scr   = (float*)(ws + 256 + (size_t)NEXP * NTOK * 4);
  int*   pair_rank  = (int*)(ws + 256 + (size_t)2 * NEXP * NTOK * 4);
  short* H          = (short*)(ws + 256 + (size_t)3 * NEXP * NTOK * 4);

  const size_t H_BYTES = (size_t)NTOK * NSEL * HIDP * 2;
  short* xbuf = (short*)((char*)H + H_BYTES);
  short* wgb  = xbuf + (size_t)NTOK * D_MODEL;
  short* wub  = wgb + (size_t)NEXP * HIDP * D_MODEL;
  short* wdb  = wub + (size_t)NEXP * HIDP * D_MODEL;
  short* Yk   = wdb + (size_t)NEXP * HIDP * D_MODEL;

  const size_t NEED_STORE = ((char*)(Yk + (size_t)NSEL * NTOK * D_MODEL)) - ws;
  const bool store_path = ws_size >= NEED_STORE;

  hipLaunchKernelGGL(zero_meta_kernel, dim3(1), dim3(64), 0, stream, counts, importance);
  hipLaunchKernelGGL(gate_conv_kernel, dim3(8192), dim3(256), 0, stream,
                     x, wgate, counts, importance, pair_tok, pair_scr, pair_rank, xbuf,
                     w_g, w_u, wgb, wub, w_d, wdb);
  hipLaunchKernelGGL(scan_loss_kernel, dim3(1), dim3(64), 0, stream,
                     counts, importance, offs, loss_out);
  hipLaunchKernelGGL(stage1b_kernel, dim3(11 * 512), dim3(256), 0, stream,
                     xbuf, wgb, wub, counts, offs, pair_tok, pair_scr, H);

  if (store_path) {
    hipLaunchKernelGGL(stage2s_kernel, dim3(16 * 512), dim3(512), 0, stream,
                       H, wdb, counts, offs, pair_tok, pair_rank, Yk);
    hipLaunchKernelGGL(reduce_y_kernel, dim3(NTOK * D_MODEL / 8 / 256), dim3(256), 0, stream,
                       Yk, y);
  } else {
    hipLaunchKernelGGL(zero_y_kernel, dim3(16384), dim3(256), 0, stream, y);
    hipLaunchKernelGGL(stage2a_kernel, dim3(32 * 512), dim3(256), 0, stream,
                       H, wdb, counts, offs, pair_tok, y);
  }
}